// Round 1
// baseline (412.503 us; speedup 1.0000x reference)
//
#include <hip/hip_runtime.h>
#include <math.h>

#define NEG_SLOPE 0.1f

constexpr int Bn = 512;
constexpr int Sn = 256;
constexpr int Dn = 256;
constexpr int Mn = Bn * Sn; // 131072

typedef short bf16x8 __attribute__((ext_vector_type(8))); // 8 bf16 in 4 VGPRs
typedef float f32x4 __attribute__((ext_vector_type(4)));

__device__ inline ushort f2bf(float f) { // round-to-nearest-even bf16 bits
  uint u = __float_as_uint(f);
  uint r = u + 0x7FFFu + ((u >> 16) & 1u);
  return (ushort)(r >> 16);
}

// ---------------------------------------------------------------------------
// Kernel 0: W1 (fp32 [e][d]) -> bf16 (hi only; lo terms contribute ~1e-3,
// far below the 0.008 bf16-storage floor of whT).
// ---------------------------------------------------------------------------
__global__ __launch_bounds__(256) void k_prep(const float* __restrict__ w1,
                                              ushort* __restrict__ w1h) {
  int idx = blockIdx.x * 256 + threadIdx.x;
  w1h[idx] = f2bf(w1[idx]);
}

// ---------------------------------------------------------------------------
// Kernel 0b: v_l[d] = sum_e W1[e][d]*a_l[e]; v_r likewise; c_l = b1.a_l etc.
// vlr[0:256]=v_l, [256:512]=v_r, [512]=c_l, [513]=c_r. vlr pre-zeroed.
// e_l[m] = x[m,:].v_l + c_l  EXACTLY in fp32 (softmax exponent precision).
// ---------------------------------------------------------------------------
__global__ __launch_bounds__(256) void k_vec(const float* __restrict__ w1,
                                             const float* __restrict__ a_w,
                                             const float* __restrict__ b1,
                                             float* __restrict__ vlr) {
  int d = threadIdx.x;
  int e0 = blockIdx.x * 32;
  float vl = 0.f, vr = 0.f;
  for (int e = e0; e < e0 + 32; ++e) {
    float w = w1[(size_t)e * 256 + d];
    vl += w * a_w[e];
    vr += w * a_w[256 + e];
  }
  atomicAdd(&vlr[d], vl);
  atomicAdd(&vlr[256 + d], vr);
  if (blockIdx.x == 0) {
    float pl = b1[d] * a_w[d], pr = b1[d] * a_w[256 + d];
#pragma unroll
    for (int o = 1; o < 64; o <<= 1) {
      pl += __shfl_xor(pl, o);
      pr += __shfl_xor(pr, o);
    }
    if ((threadIdx.x & 63) == 0) {
      atomicAdd(&vlr[512], pl);
      atomicAdd(&vlr[513], pr);
    }
  }
}

// ---------------------------------------------------------------------------
// Kernel 1: Wh = x @ W1^T + b1, single bf16 MFMA term.
// Fused: exact fp32 e_l/e_r dots (from the fp32 staging loads, against v_l/v_r)
// and bf16 Wh^T write via LDS transpose ([b][d][s] = aggregation B layout).
// ---------------------------------------------------------------------------
__global__ __launch_bounds__(256) void k_gemm1(const float* __restrict__ x,
                                               const ushort* __restrict__ w1h,
                                               const float* __restrict__ b1,
                                               const float* __restrict__ vlr,
                                               ushort* __restrict__ whT,
                                               float* __restrict__ e_l,
                                               float* __restrict__ e_r) {
  __shared__ __align__(16) ushort smem[256 * 72]; // union: Ah[64][72] | T[256][72]
  __shared__ float vl_s[256], vr_s[256];
  ushort* Ah = smem;
  ushort* T = smem;

  const int t = threadIdx.x;
  const int wave = t >> 6, lane = t & 63;
  const int q = lane >> 4, c = lane & 15;
  const int row0 = blockIdx.x * 64;
  const int n0 = wave * 64;

  vl_s[t] = vlr[t];
  vr_s[t] = vlr[256 + t];

  f32x4 acc[4][4];
#pragma unroll
  for (int mi = 0; mi < 4; ++mi)
#pragma unroll
    for (int nt = 0; nt < 4; ++nt) acc[mi][nt] = (f32x4){0.f, 0.f, 0.f, 0.f};

  const int r = t >> 2;         // 0..63 staging row
  const int kq = (t & 3) << 4;  // 0,16,32,48
  const float* xrow = x + (size_t)(row0 + r) * 256 + kq;
  float sl = 0.f, sr = 0.f;

  for (int k0 = 0; k0 < 256; k0 += 64) {
    float4 v0 = *(const float4*)(xrow + k0 + 0);
    float4 v1 = *(const float4*)(xrow + k0 + 4);
    float4 v2 = *(const float4*)(xrow + k0 + 8);
    float4 v3 = *(const float4*)(xrow + k0 + 12);
    __syncthreads(); // prior iter's LDS reads done (and vl_s visible, 1st iter)
    {
      float vv[16] = {v0.x, v0.y, v0.z, v0.w, v1.x, v1.y, v1.z, v1.w,
                      v2.x, v2.y, v2.z, v2.w, v3.x, v3.y, v3.z, v3.w};
#pragma unroll
      for (int j = 0; j < 16; ++j) {
        sl += vv[j] * vl_s[k0 + kq + j];
        sr += vv[j] * vr_s[k0 + kq + j];
      }
#pragma unroll
      for (int j = 0; j < 4; ++j) {
        ushort4 h;
        ushort* hp = (ushort*)&h;
#pragma unroll
        for (int e = 0; e < 4; ++e) hp[e] = f2bf(vv[j * 4 + e]);
        *(ushort4*)&Ah[r * 72 + kq + j * 4] = h;
      }
    }
    __syncthreads();

#pragma unroll
    for (int kk = 0; kk < 64; kk += 32) {
      bf16x8 bh[4];
#pragma unroll
      for (int nt = 0; nt < 4; ++nt)
        bh[nt] = *(const bf16x8*)(w1h + (size_t)(n0 + nt * 16 + c) * 256 + (k0 + kk) + q * 8);
#pragma unroll
      for (int mi = 0; mi < 4; ++mi) {
        bf16x8 ah = *(const bf16x8*)&Ah[(mi * 16 + c) * 72 + kk + q * 8];
#pragma unroll
        for (int nt = 0; nt < 4; ++nt)
          acc[mi][nt] = __builtin_amdgcn_mfma_f32_16x16x32_bf16(ah, bh[nt], acc[mi][nt], 0, 0, 0);
      }
    }
  }

  // exact fp32 e_l/e_r: reduce the 4 k-subranges (lanes t, t^1, t^2 same wave)
  sl += __shfl_xor(sl, 1); sl += __shfl_xor(sl, 2);
  sr += __shfl_xor(sr, 1); sr += __shfl_xor(sr, 2);
  if ((t & 3) == 0) {
    e_l[row0 + r] = sl + vlr[512];
    e_r[row0 + r] = sr + vlr[513];
  }

  // +b1, transpose to Wh^T bf16 via LDS, coalesced global write
  float b1v[4];
#pragma unroll
  for (int nt = 0; nt < 4; ++nt) b1v[nt] = b1[n0 + nt * 16 + c];
  __syncthreads(); // Ah reads done before T overwrite (union)
#pragma unroll
  for (int mi = 0; mi < 4; ++mi)
#pragma unroll
    for (int nt = 0; nt < 4; ++nt) {
      ushort4 h;
      ushort* hp = (ushort*)&h;
#pragma unroll
      for (int reg = 0; reg < 4; ++reg) hp[reg] = f2bf(acc[mi][nt][reg] + b1v[nt]);
      *(ushort4*)&T[(size_t)(n0 + nt * 16 + c) * 72 + mi * 16 + q * 4] = h;
    }
  __syncthreads();
  {
    const int b = row0 >> 8, s0 = row0 & 255;
    ushort* dst = whT + ((size_t)b * 256 + t) * 256 + s0;
#pragma unroll
    for (int j = 0; j < 8; ++j)
      *(uint4*)(dst + j * 8) = *(const uint4*)&T[t * 72 + j * 8];
  }
}

// ---------------------------------------------------------------------------
// Kernel 2: per (b, 64-row i-tile): scores -> exp (no max-pass; s <~ 25)
// -> unnormalized p bf16 (hi only) in LDS -> 1-term MFMA p @ Wh^T ->
// normalize by fp32 row-sum -> ELU -> out.
// ---------------------------------------------------------------------------
__global__ __launch_bounds__(256) void k_attn(const ushort* __restrict__ whT,
                                              const float* __restrict__ pos,
                                              const float* __restrict__ e_l,
                                              const float* __restrict__ e_r,
                                              const float* __restrict__ a_b,
                                              float* __restrict__ out) {
  __shared__ __align__(16) ushort ph[64 * 264]; // 33.8 KB
  __shared__ __align__(16) float er_s[256];
  __shared__ float el_s[64];
  __shared__ float rsum[64];

  const int t = threadIdx.x;
  const int wave = t >> 6, lane = t & 63;
  const int q = lane >> 4, c = lane & 15;
  const int b = blockIdx.y, i0 = blockIdx.x * 64;

  er_s[t] = e_r[b * 256 + t];
  if (t < 64) el_s[t] = e_l[b * 256 + i0 + t];
  __syncthreads();

  const float ab = a_b[0];
  const float* posb = pos + ((size_t)b * 256 + i0) * 256;
#pragma unroll 4
  for (int ii = 0; ii < 16; ++ii) {
    int i = ii * 4 + wave; // wave owns whole row i
    float4 pv = *(const float4*)(posb + (size_t)i * 256 + lane * 4);
    float el = el_s[i];
    float4 er = *(const float4*)&er_s[lane * 4];
    float s0 = el + er.x + ab; s0 = (s0 >= 0.f) ? s0 : NEG_SLOPE * s0; s0 += pv.x;
    float s1 = el + er.y + ab; s1 = (s1 >= 0.f) ? s1 : NEG_SLOPE * s1; s1 += pv.y;
    float s2 = el + er.z + ab; s2 = (s2 >= 0.f) ? s2 : NEG_SLOPE * s2; s2 += pv.z;
    float s3 = el + er.w + ab; s3 = (s3 >= 0.f) ? s3 : NEG_SLOPE * s3; s3 += pv.w;
    float e0 = __expf(s0), e1 = __expf(s1), e2 = __expf(s2), e3 = __expf(s3);
    float rs = e0 + e1 + e2 + e3;
#pragma unroll
    for (int off = 1; off < 64; off <<= 1) rs += __shfl_xor(rs, off);
    ushort4 h;
    ushort* hp = (ushort*)&h;
    hp[0] = f2bf(e0); hp[1] = f2bf(e1); hp[2] = f2bf(e2); hp[3] = f2bf(e3);
    *(ushort4*)&ph[i * 264 + lane * 4] = h;
    if (lane == 0) rsum[i] = rs;
  }
  __syncthreads();

  f32x4 acc[4][4];
#pragma unroll
  for (int mi = 0; mi < 4; ++mi)
#pragma unroll
    for (int nt = 0; nt < 4; ++nt) acc[mi][nt] = (f32x4){0.f, 0.f, 0.f, 0.f};

  const int n0 = wave * 64;
  const ushort* wb = whT + (size_t)b * 65536;
  for (int kk = 0; kk < 256; kk += 32) {
    bf16x8 bfr[4];
#pragma unroll
    for (int nt = 0; nt < 4; ++nt)
      bfr[nt] = *(const bf16x8*)(wb + (size_t)(n0 + nt * 16 + c) * 256 + kk + q * 8);
#pragma unroll
    for (int mi = 0; mi < 4; ++mi) {
      bf16x8 ah = *(const bf16x8*)&ph[(mi * 16 + c) * 264 + kk + q * 8];
#pragma unroll
      for (int nt = 0; nt < 4; ++nt)
        acc[mi][nt] = __builtin_amdgcn_mfma_f32_16x16x32_bf16(ah, bfr[nt], acc[mi][nt], 0, 0, 0);
    }
  }

  // epilogue: normalize, ELU, store
  float* outb = out + ((size_t)b * 256 + i0) * 256;
#pragma unroll
  for (int mi = 0; mi < 4; ++mi) {
    float alpha[4];
#pragma unroll
    for (int reg = 0; reg < 4; ++reg) alpha[reg] = 1.0f / rsum[mi * 16 + q * 4 + reg];
#pragma unroll
    for (int nt = 0; nt < 4; ++nt)
#pragma unroll
      for (int reg = 0; reg < 4; ++reg) {
        float v = acc[mi][nt][reg] * alpha[reg];
        v = (v > 0.f) ? v : (__expf(v) - 1.0f);
        outb[(size_t)(mi * 16 + q * 4 + reg) * 256 + n0 + nt * 16 + c] = v;
      }
  }
}

// ---------------------------------------------------------------------------
extern "C" void kernel_launch(void* const* d_in, const int* in_sizes, int n_in,
                              void* d_out, int out_size, void* d_ws, size_t ws_size,
                              hipStream_t stream) {
  const float* x   = (const float*)d_in[0];
  const float* pos = (const float*)d_in[1];
  const float* w1  = (const float*)d_in[2];
  const float* b1  = (const float*)d_in[3];
  const float* a_w = (const float*)d_in[4];
  const float* a_b = (const float*)d_in[5];
  float* out = (float*)d_out;

  ushort* w1h = (ushort*)d_ws;                    // 65536 ushort (128 KB)
  ushort* whT = w1h + 65536;                      // 33554432 ushort (64 MB)
  float*  e_l = (float*)(whT + (size_t)33554432); // 131072
  float*  e_r = e_l + Mn;                         // 131072
  float*  vlr = e_r + Mn;                         // 514 floats

  hipMemsetAsync(vlr, 0, 514 * sizeof(float), stream);
  k_prep<<<dim3(256), dim3(256), 0, stream>>>(w1, w1h);
  k_vec<<<dim3(8), dim3(256), 0, stream>>>(w1, a_w, b1, vlr);
  k_gemm1<<<dim3(Mn / 64), dim3(256), 0, stream>>>(x, w1h, b1, vlr, whT, e_l, e_r);
  k_attn<<<dim3(Sn / 64, Bn), dim3(256), 0, stream>>>(whT, pos, e_l, e_r, a_b, out);
}

// Round 2
// 399.434 us; speedup vs baseline: 1.0327x; 1.0327x over previous
//
#include <hip/hip_runtime.h>
#include <math.h>

#define NEG_SLOPE 0.1f

constexpr int Bn = 512;
constexpr int Sn = 256;
constexpr int Dn = 256;
constexpr int Mn = Bn * Sn; // 131072

typedef short bf16x8 __attribute__((ext_vector_type(8))); // 8 bf16 in 4 VGPRs
typedef float f32x4 __attribute__((ext_vector_type(4)));

__device__ inline ushort f2bf(float f) { // round-to-nearest-even bf16 bits
  uint u = __float_as_uint(f);
  uint r = u + 0x7FFFu + ((u >> 16) & 1u);
  return (ushort)(r >> 16);
}

// ---------------------------------------------------------------------------
// Kernel 0: W1 (fp32 [e][d]) -> bf16 (hi only).
// ---------------------------------------------------------------------------
__global__ __launch_bounds__(256) void k_prep(const float* __restrict__ w1,
                                              ushort* __restrict__ w1h) {
  int idx = blockIdx.x * 256 + threadIdx.x;
  w1h[idx] = f2bf(w1[idx]);
}

// ---------------------------------------------------------------------------
// Kernel 0b: v_l[d] = sum_e W1[e][d]*a_l[e]; v_r likewise; c_l = b1.a_l etc.
// ---------------------------------------------------------------------------
__global__ __launch_bounds__(256) void k_vec(const float* __restrict__ w1,
                                             const float* __restrict__ a_w,
                                             const float* __restrict__ b1,
                                             float* __restrict__ vlr) {
  int d = threadIdx.x;
  int e0 = blockIdx.x * 32;
  float vl = 0.f, vr = 0.f;
  for (int e = e0; e < e0 + 32; ++e) {
    float w = w1[(size_t)e * 256 + d];
    vl += w * a_w[e];
    vr += w * a_w[256 + e];
  }
  atomicAdd(&vlr[d], vl);
  atomicAdd(&vlr[256 + d], vr);
  if (blockIdx.x == 0) {
    float pl = b1[d] * a_w[d], pr = b1[d] * a_w[256 + d];
#pragma unroll
    for (int o = 1; o < 64; o <<= 1) {
      pl += __shfl_xor(pl, o);
      pr += __shfl_xor(pr, o);
    }
    if ((threadIdx.x & 63) == 0) {
      atomicAdd(&vlr[512], pl);
      atomicAdd(&vlr[513], pr);
    }
  }
}

// ---------------------------------------------------------------------------
// Kernel 1: Wh = x @ W1^T + b1 (bf16 MFMA), fused e_l/e_r fp32 dots + Wh^T
// bf16 write via LDS transpose. (unchanged this round)
// ---------------------------------------------------------------------------
__global__ __launch_bounds__(256) void k_gemm1(const float* __restrict__ x,
                                               const ushort* __restrict__ w1h,
                                               const float* __restrict__ b1,
                                               const float* __restrict__ vlr,
                                               ushort* __restrict__ whT,
                                               float* __restrict__ e_l,
                                               float* __restrict__ e_r) {
  __shared__ __align__(16) ushort smem[256 * 72]; // union: Ah[64][72] | T[256][72]
  __shared__ float vl_s[256], vr_s[256];
  ushort* Ah = smem;
  ushort* T = smem;

  const int t = threadIdx.x;
  const int wave = t >> 6, lane = t & 63;
  const int q = lane >> 4, c = lane & 15;
  const int row0 = blockIdx.x * 64;
  const int n0 = wave * 64;

  vl_s[t] = vlr[t];
  vr_s[t] = vlr[256 + t];

  f32x4 acc[4][4];
#pragma unroll
  for (int mi = 0; mi < 4; ++mi)
#pragma unroll
    for (int nt = 0; nt < 4; ++nt) acc[mi][nt] = (f32x4){0.f, 0.f, 0.f, 0.f};

  const int r = t >> 2;         // 0..63 staging row
  const int kq = (t & 3) << 4;  // 0,16,32,48
  const float* xrow = x + (size_t)(row0 + r) * 256 + kq;
  float sl = 0.f, sr = 0.f;

  for (int k0 = 0; k0 < 256; k0 += 64) {
    float4 v0 = *(const float4*)(xrow + k0 + 0);
    float4 v1 = *(const float4*)(xrow + k0 + 4);
    float4 v2 = *(const float4*)(xrow + k0 + 8);
    float4 v3 = *(const float4*)(xrow + k0 + 12);
    __syncthreads(); // prior iter's LDS reads done (and vl_s visible, 1st iter)
    {
      float vv[16] = {v0.x, v0.y, v0.z, v0.w, v1.x, v1.y, v1.z, v1.w,
                      v2.x, v2.y, v2.z, v2.w, v3.x, v3.y, v3.z, v3.w};
#pragma unroll
      for (int j = 0; j < 16; ++j) {
        sl += vv[j] * vl_s[k0 + kq + j];
        sr += vv[j] * vr_s[k0 + kq + j];
      }
#pragma unroll
      for (int j = 0; j < 4; ++j) {
        ushort4 h;
        ushort* hp = (ushort*)&h;
#pragma unroll
        for (int e = 0; e < 4; ++e) hp[e] = f2bf(vv[j * 4 + e]);
        *(ushort4*)&Ah[r * 72 + kq + j * 4] = h;
      }
    }
    __syncthreads();

#pragma unroll
    for (int kk = 0; kk < 64; kk += 32) {
      bf16x8 bh[4];
#pragma unroll
      for (int nt = 0; nt < 4; ++nt)
        bh[nt] = *(const bf16x8*)(w1h + (size_t)(n0 + nt * 16 + c) * 256 + (k0 + kk) + q * 8);
#pragma unroll
      for (int mi = 0; mi < 4; ++mi) {
        bf16x8 ah = *(const bf16x8*)&Ah[(mi * 16 + c) * 72 + kk + q * 8];
#pragma unroll
        for (int nt = 0; nt < 4; ++nt)
          acc[mi][nt] = __builtin_amdgcn_mfma_f32_16x16x32_bf16(ah, bh[nt], acc[mi][nt], 0, 0, 0);
      }
    }
  }

  // exact fp32 e_l/e_r: reduce the 4 k-subranges (lanes t, t^1, t^2 same wave)
  sl += __shfl_xor(sl, 1); sl += __shfl_xor(sl, 2);
  sr += __shfl_xor(sr, 1); sr += __shfl_xor(sr, 2);
  if ((t & 3) == 0) {
    e_l[row0 + r] = sl + vlr[512];
    e_r[row0 + r] = sr + vlr[513];
  }

  // +b1, transpose to Wh^T bf16 via LDS, coalesced global write
  float b1v[4];
#pragma unroll
  for (int nt = 0; nt < 4; ++nt) b1v[nt] = b1[n0 + nt * 16 + c];
  __syncthreads(); // Ah reads done before T overwrite (union)
#pragma unroll
  for (int mi = 0; mi < 4; ++mi)
#pragma unroll
    for (int nt = 0; nt < 4; ++nt) {
      ushort4 h;
      ushort* hp = (ushort*)&h;
#pragma unroll
      for (int reg = 0; reg < 4; ++reg) hp[reg] = f2bf(acc[mi][nt][reg] + b1v[nt]);
      *(ushort4*)&T[(size_t)(n0 + nt * 16 + c) * 72 + mi * 16 + q * 4] = h;
    }
  __syncthreads();
  {
    const int b = row0 >> 8, s0 = row0 & 255;
    ushort* dst = whT + ((size_t)b * 256 + t) * 256 + s0;
#pragma unroll
    for (int j = 0; j < 8; ++j)
      *(uint4*)(dst + j * 8) = *(const uint4*)&T[t * 72 + j * 8];
  }
}

// ---------------------------------------------------------------------------
// Kernel 2 (restructured): j-chunked pipeline. Per 64-col chunk:
//   issue pos loads for chunk t+1 -> scores for chunk t (from regs) ->
//   barrier -> MFMA-accumulate chunk t (double-buffered ph, 1 barrier/chunk).
// pos loads for t+1 stay in flight across scores+barrier+MFMA of chunk t.
// Row-sums accumulate per-thread across chunks; single 4-step reduce at end.
// ---------------------------------------------------------------------------
__global__ __launch_bounds__(256) void k_attn(const ushort* __restrict__ whT,
                                              const float* __restrict__ pos,
                                              const float* __restrict__ e_l,
                                              const float* __restrict__ e_r,
                                              const float* __restrict__ a_b,
                                              float* __restrict__ out) {
  __shared__ __align__(16) ushort ph[2][64 * 72]; // 18.4 KB dbuf
  __shared__ __align__(16) float er_s[256];
  __shared__ float el_s[64];
  __shared__ float rsum[64];

  const int t = threadIdx.x;
  const int wave = t >> 6, lane = t & 63;
  const int q = lane >> 4, c = lane & 15;
  const int b = blockIdx.y, i0 = blockIdx.x * 64;

  er_s[t] = e_r[b * 256 + t];
  if (t < 64) el_s[t] = e_l[b * 256 + i0 + t];

  // scores mapping: wave owns rows [wave*16, wave*16+16).
  // inner it=0..3: row = wave*16 + it*4 + q ; cols = chunk j0 + c*4 .. +4
  const int r16 = wave * 16;
  const float ab = a_b[0];
  const float* posb = pos + ((size_t)b * 256 + i0) * 256;

  f32x4 acc[4][4];
#pragma unroll
  for (int mi = 0; mi < 4; ++mi)
#pragma unroll
    for (int nt = 0; nt < 4; ++nt) acc[mi][nt] = (f32x4){0.f, 0.f, 0.f, 0.f};

  float psum[4] = {0.f, 0.f, 0.f, 0.f};

  // prologue: pos loads for chunk 0
  float4 pv[4];
#pragma unroll
  for (int it = 0; it < 4; ++it)
    pv[it] = *(const float4*)(posb + (size_t)(r16 + it * 4 + q) * 256 + c * 4);

  __syncthreads(); // er_s / el_s visible

  const int n0 = wave * 64;
  const ushort* wb = whT + (size_t)b * 65536;

  for (int tc = 0; tc < 4; ++tc) {
    const int j0 = tc * 64;
    ushort* phb = &ph[tc & 1][0];

    // issue next chunk's pos loads (stay in flight through scores+MFMA)
    float4 pn[4];
    if (tc < 3) {
#pragma unroll
      for (int it = 0; it < 4; ++it)
        pn[it] = *(const float4*)(posb + (size_t)(r16 + it * 4 + q) * 256 + j0 + 64 + c * 4);
    }

    // scores for chunk tc from pv
    float4 er = *(const float4*)&er_s[j0 + c * 4];
#pragma unroll
    for (int it = 0; it < 4; ++it) {
      const int row = r16 + it * 4 + q;
      const float el = el_s[row];
      float s0 = el + er.x + ab; s0 = (s0 >= 0.f) ? s0 : NEG_SLOPE * s0; s0 += pv[it].x;
      float s1 = el + er.y + ab; s1 = (s1 >= 0.f) ? s1 : NEG_SLOPE * s1; s1 += pv[it].y;
      float s2 = el + er.z + ab; s2 = (s2 >= 0.f) ? s2 : NEG_SLOPE * s2; s2 += pv[it].z;
      float s3 = el + er.w + ab; s3 = (s3 >= 0.f) ? s3 : NEG_SLOPE * s3; s3 += pv[it].w;
      float e0 = __expf(s0), e1 = __expf(s1), e2 = __expf(s2), e3 = __expf(s3);
      psum[it] += e0 + e1 + e2 + e3;
      ushort4 h;
      ushort* hp = (ushort*)&h;
      hp[0] = f2bf(e0); hp[1] = f2bf(e1); hp[2] = f2bf(e2); hp[3] = f2bf(e3);
      *(ushort4*)&phb[row * 72 + c * 4] = h;
    }
    __syncthreads(); // ph[tc&1] complete; (also fences reuse of ph[tc&1] two
                     // chunks later: every wave passed this barrier only after
                     // finishing its MFMA reads of the previous occupant)

    // MFMA-accumulate this chunk
#pragma unroll
    for (int kk = 0; kk < 64; kk += 32) {
      bf16x8 bfr[4];
#pragma unroll
      for (int nt = 0; nt < 4; ++nt)
        bfr[nt] = *(const bf16x8*)(wb + (size_t)(n0 + nt * 16 + c) * 256 + j0 + kk + q * 8);
#pragma unroll
      for (int mi = 0; mi < 4; ++mi) {
        bf16x8 ah = *(const bf16x8*)&phb[(mi * 16 + c) * 72 + kk + q * 8];
#pragma unroll
        for (int nt = 0; nt < 4; ++nt)
          acc[mi][nt] = __builtin_amdgcn_mfma_f32_16x16x32_bf16(ah, bfr[nt], acc[mi][nt], 0, 0, 0);
      }
    }

#pragma unroll
    for (int it = 0; it < 4; ++it) pv[it] = pn[it];
  }

  // final row-sum reduce: psum[it] covers 4 cols x 4 chunks; sum across the
  // 16 lanes (lane&15) sharing the same row.
#pragma unroll
  for (int it = 0; it < 4; ++it) {
    float p = psum[it];
    p += __shfl_xor(p, 1);
    p += __shfl_xor(p, 2);
    p += __shfl_xor(p, 4);
    p += __shfl_xor(p, 8);
    if (c == 0) rsum[r16 + it * 4 + q] = p;
  }
  __syncthreads();

  // epilogue: normalize, ELU, store
  float* outb = out + ((size_t)b * 256 + i0) * 256;
#pragma unroll
  for (int mi = 0; mi < 4; ++mi) {
    float alpha[4];
#pragma unroll
    for (int reg = 0; reg < 4; ++reg) alpha[reg] = 1.0f / rsum[mi * 16 + q * 4 + reg];
#pragma unroll
    for (int nt = 0; nt < 4; ++nt)
#pragma unroll
      for (int reg = 0; reg < 4; ++reg) {
        float v = acc[mi][nt][reg] * alpha[reg];
        v = (v > 0.f) ? v : (__expf(v) - 1.0f);
        outb[(size_t)(mi * 16 + q * 4 + reg) * 256 + n0 + nt * 16 + c] = v;
      }
  }
}

// ---------------------------------------------------------------------------
extern "C" void kernel_launch(void* const* d_in, const int* in_sizes, int n_in,
                              void* d_out, int out_size, void* d_ws, size_t ws_size,
                              hipStream_t stream) {
  const float* x   = (const float*)d_in[0];
  const float* pos = (const float*)d_in[1];
  const float* w1  = (const float*)d_in[2];
  const float* b1  = (const float*)d_in[3];
  const float* a_w = (const float*)d_in[4];
  const float* a_b = (const float*)d_in[5];
  float* out = (float*)d_out;

  ushort* w1h = (ushort*)d_ws;                    // 65536 ushort (128 KB)
  ushort* whT = w1h + 65536;                      // 33554432 ushort (64 MB)
  float*  e_l = (float*)(whT + (size_t)33554432); // 131072
  float*  e_r = e_l + Mn;                         // 131072
  float*  vlr = e_r + Mn;                         // 514 floats

  hipMemsetAsync(vlr, 0, 514 * sizeof(float), stream);
  k_prep<<<dim3(256), dim3(256), 0, stream>>>(w1, w1h);
  k_vec<<<dim3(8), dim3(256), 0, stream>>>(w1, a_w, b1, vlr);
  k_gemm1<<<dim3(Mn / 64), dim3(256), 0, stream>>>(x, w1h, b1, vlr, whT, e_l, e_r);
  k_attn<<<dim3(Sn / 64, Bn), dim3(256), 0, stream>>>(whT, pos, e_l, e_r, a_b, out);
}

// Round 3
// 347.939 us; speedup vs baseline: 1.1856x; 1.1480x over previous
//
#include <hip/hip_runtime.h>
#include <math.h>

#define NEG_SLOPE 0.1f

constexpr int Bn = 512;
constexpr int Sn = 256;
constexpr int Dn = 256;

typedef short bf16x8 __attribute__((ext_vector_type(8)));
typedef float f32x4 __attribute__((ext_vector_type(4)));

__device__ inline ushort f2bf(float f) { // round-to-nearest-even bf16 bits
  uint u = __float_as_uint(f);
  uint r = u + 0x7FFFu + ((u >> 16) & 1u);
  return (ushort)(r >> 16);
}

// Raw barrier: drains LDS ops (cross-wave produce/consume) but NOT vmcnt —
// global prefetches stay in flight across it (unlike __syncthreads, which
// the compiler precedes with s_waitcnt vmcnt(0)).
#define BAR() asm volatile("s_waitcnt lgkmcnt(0)\n\ts_barrier" ::: "memory")

// ---------------------------------------------------------------------------
// Kernel 0 (merged prep+vec): w1h = bf16(W1); vlr = {v_l, v_r, c_l, c_r}.
// ---------------------------------------------------------------------------
__global__ __launch_bounds__(256) void k_prep_vec(const float* __restrict__ w1,
                                                  const float* __restrict__ a_w,
                                                  const float* __restrict__ b1,
                                                  ushort* __restrict__ w1h,
                                                  float* __restrict__ vlr) {
  int idx = blockIdx.x * 256 + threadIdx.x;
  w1h[idx] = f2bf(w1[idx]);
  if (blockIdx.x < 8) {
    int d = threadIdx.x;
    int e0 = blockIdx.x * 32;
    float vl = 0.f, vr = 0.f;
    for (int e = e0; e < e0 + 32; ++e) {
      float w = w1[(size_t)e * 256 + d];
      vl += w * a_w[e];
      vr += w * a_w[256 + e];
    }
    atomicAdd(&vlr[d], vl);
    atomicAdd(&vlr[256 + d], vr);
    if (blockIdx.x == 0) {
      float pl = b1[d] * a_w[d], pr = b1[d] * a_w[256 + d];
#pragma unroll
      for (int o = 1; o < 64; o <<= 1) {
        pl += __shfl_xor(pl, o);
        pr += __shfl_xor(pr, o);
      }
      if ((threadIdx.x & 63) == 0) {
        atomicAdd(&vlr[512], pl);
        atomicAdd(&vlr[513], pr);
      }
    }
  }
}

// ---------------------------------------------------------------------------
// Fused kernel: one block per b (512 threads = 8 waves).
// Phase A: Wh^T[b] (256x256 bf16, XOR-swizzled) built in LDS via MFMA
//          (two 4-wave groups x two 64-row s-tiles each), + e_l/e_r in LDS.
// Phase B: 4 i-tiles x 4 j-chunks: scores->exp->ph (dbuf) -> MFMA vs WhT-LDS
//          -> normalize/ELU/store. Raw barriers; depth-2 pos prefetch.
// HBM: x 134MB + pos 134MB in, out 134MB out. No whT round-trip.
// ---------------------------------------------------------------------------
__global__ __launch_bounds__(512) void k_fused(const float* __restrict__ x,
                                               const ushort* __restrict__ w1h,
                                               const float* __restrict__ b1,
                                               const float* __restrict__ vlr,
                                               const float* __restrict__ pos,
                                               const float* __restrict__ a_b,
                                               float* __restrict__ out) {
  __shared__ __align__(16) ushort WhT_s[65536]; // 128 KB, swizzled ^((d&7)<<3)
  __shared__ __align__(16) ushort AhPh[9216];   // 18 KB union: Ah[2][64][72] | ph[2][64][72]
  __shared__ __align__(16) float vl_s[256];
  __shared__ __align__(16) float vr_s[256];
  __shared__ __align__(16) float el_s[256];
  __shared__ __align__(16) float er_s[256];
  __shared__ float rsum[64];

  const int t = threadIdx.x;
  const int wave = t >> 6, lane = t & 63;
  const int q = lane >> 4, c = lane & 15;
  const int b = blockIdx.x;

  const float cl = vlr[512], cr = vlr[513];
  const float ab = a_b[0];

  if (t < 256) {
    vl_s[t] = vlr[t];
    vr_s[t] = vlr[256 + t];
  }

  // ---------------- Phase A ----------------
  const int g = wave >> 2;       // group 0/1 -> s-tiles {2g, 2g+1}
  const int wg = wave & 3;       // wave-in-group
  const int n0A = wg * 64;
  const int tt = t & 255;
  const int r = tt >> 2;         // staging row 0..63
  const int kq = (tt & 3) << 4;  // 0,16,32,48
  const float* xb = x + (size_t)b * 65536;
  ushort* Ahg = AhPh + g * 4608;

  float b1v[4];
#pragma unroll
  for (int nt = 0; nt < 4; ++nt) b1v[nt] = b1[n0A + nt * 16 + c];

  {
    f32x4 acc[4][4];
#pragma unroll
    for (int mi = 0; mi < 4; ++mi)
#pragma unroll
      for (int nt = 0; nt < 4; ++nt) acc[mi][nt] = (f32x4){0.f, 0.f, 0.f, 0.f};
    float sl = 0.f, sr = 0.f;

    float4 V0, V1, V2, V3, N0, N1, N2, N3;
    {
      const float* p = xb + (size_t)((g * 2) * 64 + r) * 256 + kq;
      V0 = *(const float4*)(p); V1 = *(const float4*)(p + 4);
      V2 = *(const float4*)(p + 8); V3 = *(const float4*)(p + 12);
    }

#pragma unroll
    for (int sk = 0; sk < 8; ++sk) {
      const int stile = g * 2 + (sk >> 2);
      const int k0 = (sk & 3) * 64;
      if (sk < 7) { // prefetch next k-step (rides across barriers)
        const int s2 = g * 2 + ((sk + 1) >> 2), kn = ((sk + 1) & 3) * 64;
        const float* p = xb + (size_t)(s2 * 64 + r) * 256 + kn + kq;
        N0 = *(const float4*)(p); N1 = *(const float4*)(p + 4);
        N2 = *(const float4*)(p + 8); N3 = *(const float4*)(p + 12);
      }
      BAR(); // prev MFMA's Ah reads drained (and vl_s visible, sk=0)
      {
        float vv[16] = {V0.x, V0.y, V0.z, V0.w, V1.x, V1.y, V1.z, V1.w,
                        V2.x, V2.y, V2.z, V2.w, V3.x, V3.y, V3.z, V3.w};
#pragma unroll
        for (int j = 0; j < 16; ++j) {
          sl += vv[j] * vl_s[k0 + kq + j];
          sr += vv[j] * vr_s[k0 + kq + j];
        }
#pragma unroll
        for (int j = 0; j < 4; ++j) {
          ushort4 h;
          ushort* hp = (ushort*)&h;
#pragma unroll
          for (int e = 0; e < 4; ++e) hp[e] = f2bf(vv[j * 4 + e]);
          *(ushort4*)&Ahg[r * 72 + kq + j * 4] = h;
        }
      }
      BAR(); // Ah visible

#pragma unroll
      for (int kk = 0; kk < 64; kk += 32) {
        bf16x8 bh[4];
#pragma unroll
        for (int nt = 0; nt < 4; ++nt)
          bh[nt] = *(const bf16x8*)(w1h + (size_t)(n0A + nt * 16 + c) * 256 + k0 + kk + q * 8);
#pragma unroll
        for (int mi = 0; mi < 4; ++mi) {
          bf16x8 ah = *(const bf16x8*)&Ahg[(mi * 16 + c) * 72 + kk + q * 8];
#pragma unroll
          for (int nt = 0; nt < 4; ++nt)
            acc[mi][nt] = __builtin_amdgcn_mfma_f32_16x16x32_bf16(ah, bh[nt], acc[mi][nt], 0, 0, 0);
        }
      }

      if ((sk & 3) == 3) { // end of one s-tile
        // e_l/e_r fp32 dots (exact): reduce 4 kq-quadrants
        sl += __shfl_xor(sl, 1); sl += __shfl_xor(sl, 2);
        sr += __shfl_xor(sr, 1); sr += __shfl_xor(sr, 2);
        if ((tt & 3) == 0) {
          el_s[stile * 64 + r] = sl + cl;
          er_s[stile * 64 + r] = sr + cr;
        }
        // transpose-store acc+b1 -> WhT_s (swizzled)
#pragma unroll
        for (int mi = 0; mi < 4; ++mi)
#pragma unroll
          for (int nt = 0; nt < 4; ++nt) {
            ushort4 h;
            ushort* hp = (ushort*)&h;
#pragma unroll
            for (int reg = 0; reg < 4; ++reg) hp[reg] = f2bf(acc[mi][nt][reg] + b1v[nt]);
            uint idx = (uint)(n0A + nt * 16 + c) * 256 + stile * 64 + mi * 16 + q * 4;
            idx ^= (uint)((c & 7) << 3);
            *(ushort4*)&WhT_s[idx] = h;
            acc[mi][nt] = (f32x4){0.f, 0.f, 0.f, 0.f};
          }
        sl = 0.f; sr = 0.f;
      }
      if (sk < 7) { V0 = N0; V1 = N1; V2 = N2; V3 = N3; }
    }
  }

  // ---------------- Phase B ----------------
  const float* posb = pos + (size_t)b * 65536;
  // depth-2 pos prefetch: Pa = chunk gc, Pb = gc+1, Pc = gc+2 (issued at top)
  float4 Pa0, Pa1, Pb0, Pb1, Pc0, Pc1;
  {
    const float* p0 = posb + (size_t)(wave * 8 + q) * 256 + c * 4;        // gc=0
    Pa0 = *(const float4*)p0; Pa1 = *(const float4*)(p0 + 1024);
    const float* p1 = posb + (size_t)(wave * 8 + q) * 256 + 64 + c * 4;   // gc=1
    Pb0 = *(const float4*)p1; Pb1 = *(const float4*)(p1 + 1024);
  }
  BAR(); // WhT_s + el_s/er_s complete; AhPh free for ph

  const int n0B = wave * 32;
  f32x4 accB[4][2];
#pragma unroll
  for (int mi = 0; mi < 4; ++mi)
#pragma unroll
    for (int nt = 0; nt < 2; ++nt) accB[mi][nt] = (f32x4){0.f, 0.f, 0.f, 0.f};
  float psum0 = 0.f, psum1 = 0.f;

#pragma unroll
  for (int gc = 0; gc < 16; ++gc) {
    const int itile = gc >> 2, tc = gc & 3;
    if (gc < 14) { // prefetch chunk gc+2
      const int i2 = (gc + 2) >> 2, t2 = (gc + 2) & 3;
      const float* p = posb + (size_t)(i2 * 64 + wave * 8 + q) * 256 + t2 * 64 + c * 4;
      Pc0 = *(const float4*)p; Pc1 = *(const float4*)(p + 1024);
    }
    ushort* phb = AhPh + (gc & 1) * 4608;

    // scores for chunk gc (consume Pa)
    float4 er = *(const float4*)&er_s[tc * 64 + c * 4];
#pragma unroll
    for (int it2 = 0; it2 < 2; ++it2) {
      const int rl = wave * 8 + it2 * 4 + q;
      const float el = el_s[itile * 64 + rl];
      float4 pv = it2 ? Pa1 : Pa0;
      float s0 = el + er.x + ab; s0 = (s0 >= 0.f) ? s0 : NEG_SLOPE * s0; s0 += pv.x;
      float s1 = el + er.y + ab; s1 = (s1 >= 0.f) ? s1 : NEG_SLOPE * s1; s1 += pv.y;
      float s2 = el + er.z + ab; s2 = (s2 >= 0.f) ? s2 : NEG_SLOPE * s2; s2 += pv.z;
      float s3 = el + er.w + ab; s3 = (s3 >= 0.f) ? s3 : NEG_SLOPE * s3; s3 += pv.w;
      float e0 = __expf(s0), e1 = __expf(s1), e2 = __expf(s2), e3 = __expf(s3);
      if (it2) psum1 += e0 + e1 + e2 + e3; else psum0 += e0 + e1 + e2 + e3;
      ushort4 h;
      ushort* hp = (ushort*)&h;
      hp[0] = f2bf(e0); hp[1] = f2bf(e1); hp[2] = f2bf(e2); hp[3] = f2bf(e3);
      *(ushort4*)&phb[rl * 72 + c * 4] = h;
    }
    BAR(); // ph visible (prev buffer's MFMA reads drained at previous BAR)

    // MFMA: P-chunk @ WhT (LDS, swizzled)
#pragma unroll
    for (int kk = 0; kk < 64; kk += 32) {
      bf16x8 bfr[2];
#pragma unroll
      for (int nt = 0; nt < 2; ++nt) {
        uint idx = (uint)(n0B + nt * 16 + c) * 256 + tc * 64 + kk + q * 8;
        idx ^= (uint)((c & 7) << 3);
        bfr[nt] = *(const bf16x8*)&WhT_s[idx];
      }
#pragma unroll
      for (int mi = 0; mi < 4; ++mi) {
        bf16x8 ah = *(const bf16x8*)&phb[(mi * 16 + c) * 72 + kk + q * 8];
#pragma unroll
        for (int nt = 0; nt < 2; ++nt)
          accB[mi][nt] = __builtin_amdgcn_mfma_f32_16x16x32_bf16(ah, bfr[nt], accB[mi][nt], 0, 0, 0);
      }
    }

    if (tc == 3) { // i-tile epilogue
      float p0v = psum0, p1v = psum1;
      p0v += __shfl_xor(p0v, 1); p0v += __shfl_xor(p0v, 2);
      p0v += __shfl_xor(p0v, 4); p0v += __shfl_xor(p0v, 8);
      p1v += __shfl_xor(p1v, 1); p1v += __shfl_xor(p1v, 2);
      p1v += __shfl_xor(p1v, 4); p1v += __shfl_xor(p1v, 8);
      if (c == 0) {
        rsum[wave * 8 + q] = p0v;
        rsum[wave * 8 + 4 + q] = p1v;
      }
      psum0 = 0.f; psum1 = 0.f;
      BAR(); // rsum visible
      float* outb = out + ((size_t)b * 256 + itile * 64) * 256;
#pragma unroll
      for (int mi = 0; mi < 4; ++mi) {
        float alpha[4];
#pragma unroll
        for (int reg = 0; reg < 4; ++reg) alpha[reg] = 1.0f / rsum[mi * 16 + q * 4 + reg];
#pragma unroll
        for (int nt = 0; nt < 2; ++nt)
#pragma unroll
          for (int reg = 0; reg < 4; ++reg) {
            float v = accB[mi][nt][reg] * alpha[reg];
            v = (v > 0.f) ? v : (__expf(v) - 1.0f);
            outb[(size_t)(mi * 16 + q * 4 + reg) * 256 + n0B + nt * 16 + c] = v;
            accB[mi][nt][reg] = 0.f;
          }
      }
    }
    Pa0 = Pb0; Pa1 = Pb1; Pb0 = Pc0; Pb1 = Pc1;
  }
}

// ---------------------------------------------------------------------------
extern "C" void kernel_launch(void* const* d_in, const int* in_sizes, int n_in,
                              void* d_out, int out_size, void* d_ws, size_t ws_size,
                              hipStream_t stream) {
  const float* x   = (const float*)d_in[0];
  const float* pos = (const float*)d_in[1];
  const float* w1  = (const float*)d_in[2];
  const float* b1  = (const float*)d_in[3];
  const float* a_w = (const float*)d_in[4];
  const float* a_b = (const float*)d_in[5];
  float* out = (float*)d_out;

  ushort* w1h = (ushort*)d_ws;          // 65536 ushort (128 KB)
  float*  vlr = (float*)(w1h + 65536);  // 514 floats

  hipMemsetAsync(vlr, 0, 514 * sizeof(float), stream);
  k_prep_vec<<<dim3(256), dim3(256), 0, stream>>>(w1, a_w, b1, w1h, vlr);
  k_fused<<<dim3(Bn), dim3(512), 0, stream>>>(x, w1h, b1, vlr, pos, a_b, out);
}